// Round 2
// baseline (355.805 us; speedup 1.0000x reference)
//
#include <hip/hip_runtime.h>
#include <hip/hip_bf16.h>

#define HWHW 65536   // 256*256
#define LN1E4_32 0.28782313662425572f   // ln(10000)/32

typedef __attribute__((ext_vector_type(8))) short short8;
typedef __attribute__((ext_vector_type(4))) float f32x4;

__device__ __forceinline__ short f2bf(float f) {
  union { __hip_bfloat16 h; short s; } u;
  u.h = __float2bfloat16(f);
  return u.s;
}

// ---------------- pre-pass: pack q_w/k_w/v_w (fp32, 64x128) into bf16 MFMA
// B-fragment order in ws:  slot = mat*1024 + (ks*4+nt)*64 + lane,  8 bf16/slot.
// B layout (16x16x32): n = nt*16 + (lane&15), k = ks*32 + (lane>>4)*8 + j.
__global__ void pack_weights(const float* __restrict__ qw,
                             const float* __restrict__ kw,
                             const float* __restrict__ vw,
                             __hip_bfloat16* __restrict__ wfrag) {
  int slot = blockIdx.x * 256 + threadIdx.x;       // 3072 slots total
  int mat = slot >> 10, rem = slot & 1023;
  int ksnt = rem >> 6, lane_s = rem & 63;
  int ks = ksnt >> 2, nt = ksnt & 3;
  int n  = nt * 16 + (lane_s & 15);
  int k0 = ks * 32 + (lane_s >> 4) * 8;
  const float* w = (mat == 0) ? qw : (mat == 1) ? kw : vw;
  w += n * 128 + k0;
  __hip_bfloat16* dst = wfrag + slot * 8;
#pragma unroll
  for (int j = 0; j < 8; ++j) dst[j] = __float2bfloat16(w[j]);
}

// ---------------- main kernel: 64 pixels / block, 4 waves, no K/V staging.
// LDS: pos table 4x132 fp32 + q-stage 64x68 fp32  ≈ 19.5 KB  -> LDS allows 8 blk/CU
__global__ __launch_bounds__(256, 3)
void iw_main(const float* __restrict__ feat_supp, const float* __restrict__ flow,
             const float* __restrict__ feat_curr,
             const short8* __restrict__ wfrag,
             const float* __restrict__ q_b, const float* __restrict__ k_b,
             const float* __restrict__ v_b, float* __restrict__ out)
{
  __shared__ float pos_lds[4 * 132];
  __shared__ float q_sf[64 * 68];

  const int tid = threadIdx.x;
  const int bi  = blockIdx.x;
  const int b   = bi >> 10;
  const int hw0 = (bi & 1023) << 6;
  const int lane = tid & 63, wv = tid >> 6;
  const int quad = lane >> 4, l15 = lane & 15;

  // window pos-bias table (card = U-1 = 1)
  for (int idx = tid; idx < 512; idx += 256) {
    int uv = idx >> 7, k = idx & 127;
    float val = (k < 64) ? (float)(uv >> 1) : (float)(uv & 1);
    val *= 6.2831853071795864f / 1.000001f;
    int i = k & 63, f = i >> 1;
    float arg = val * __expf(-(float)f * LN1E4_32);
    pos_lds[uv * 132 + k] = (i & 1) ? __cosf(arg) : __sinf(arg);
  }
  __syncthreads();

  // per-lane inverse dim_t: f = a*16 + quad*4 + jj
  float invd[2][4];
#pragma unroll
  for (int a = 0; a < 2; ++a)
#pragma unroll
    for (int jj = 0; jj < 4; ++jj)
      invd[a][jj] = __expf(-(float)(a * 16 + quad * 4 + jj) * LN1E4_32);

  // ---------- Q phase: A-frag (m = l15 -> pixel), GEMM, stage scaled q to LDS
  {
    const int qpix = hw0 + wv * 16 + l15;
    float flx = flow[(b * HWHW + qpix) * 2 + 0];
    float fly = flow[(b * HWHW + qpix) * 2 + 1];
    float gy = (float)(qpix >> 8) + fly;
    float gx = (float)(qpix & 255) + flx;
    float vy = (gy - floorf(gy)) * (6.2831853071795864f / 2.000001f);
    float vx = (gx - floorf(gx)) * (6.2831853071795864f / 2.000001f);

    short8 qa[4];
#pragma unroll
    for (int ks = 0; ks < 4; ++ks) {
      float val = (ks < 2) ? vy : vx;
#pragma unroll
      for (int jj = 0; jj < 4; ++jj) {
        int c = ks * 16 + quad * 4 + jj;
        float feat = feat_curr[(b * 64 + c) * HWHW + qpix];
        float arg = val * invd[ks & 1][jj];
        qa[ks][jj * 2]     = f2bf(feat + __sinf(arg));
        qa[ks][jj * 2 + 1] = f2bf(feat + __cosf(arg));
      }
    }

    f32x4 qacc[4];
#pragma unroll
    for (int nt = 0; nt < 4; ++nt) qacc[nt] = (f32x4){0.f, 0.f, 0.f, 0.f};
#pragma unroll
    for (int ks = 0; ks < 4; ++ks)
#pragma unroll
      for (int nt = 0; nt < 4; ++nt)
        qacc[nt] = __builtin_amdgcn_mfma_f32_16x16x32_bf16(
            qa[ks], wfrag[(ks * 4 + nt) * 64 + lane], qacc[nt], 0, 0, 0);

    // stage (q + qb) * scale ; D rows: pixel = quad*4 + r
#pragma unroll
    for (int nt = 0; nt < 4; ++nt) {
      float qb = q_b[nt * 16 + l15];
#pragma unroll
      for (int r = 0; r < 4; ++r)
        q_sf[(wv * 16 + quad * 4 + r) * 68 + nt * 16 + l15] =
            (qacc[nt][r] + qb) * 0.35355339059327373f;
    }
  }
  __syncthreads();

  // pos-bias fragment values for this lane's uv (constant over mt)
  const int uvl = l15 & 3;
  float pb[4][8];
#pragma unroll
  for (int ks = 0; ks < 4; ++ks)
#pragma unroll
    for (int j = 0; j < 8; ++j)
      pb[ks][j] = pos_lds[uvl * 132 + ks * 32 + quad * 8 + j];

  float kb[4], vb[4];
#pragma unroll
  for (int nt = 0; nt < 4; ++nt) {
    kb[nt] = k_b[nt * 16 + l15];
    vb[nt] = v_b[nt * 16 + l15];
  }

  const int prow = l15 >> 2;

  // ---------- K/V + attention, 4 pixels-per-lane at a time (mt loop)
  for (int mt = 0; mt < 4; ++mt) {
    // A-frag rows: m = l15 = prow*4 + uv  -> gather pixel mt*4+prow, window uvl
    const int gpix = hw0 + wv * 16 + mt * 4 + prow;
    float fy = flow[(b * HWHW + gpix) * 2 + 1] + (float)(gpix >> 8);
    float fx = flow[(b * HWHW + gpix) * 2 + 0] + (float)(gpix & 255);
    int yy = min(max((int)floorf(fy) + (uvl >> 1), 0), 255);
    int xx = min(max((int)floorf(fx) + (uvl & 1), 0), 255);
    int lin = yy * 256 + xx;

    short8 ka[4];
#pragma unroll
    for (int ks = 0; ks < 4; ++ks)
#pragma unroll
      for (int jj = 0; jj < 4; ++jj) {
        int c = ks * 16 + quad * 4 + jj;
        float gv = feat_supp[(b * 64 + c) * HWHW + lin];
        ka[ks][jj * 2]     = f2bf(gv + pb[ks][jj * 2]);
        ka[ks][jj * 2 + 1] = f2bf(gv + pb[ks][jj * 2 + 1]);
      }

    f32x4 kacc[4], vacc[4];
#pragma unroll
    for (int nt = 0; nt < 4; ++nt) {
      kacc[nt] = (f32x4){0.f, 0.f, 0.f, 0.f};
      vacc[nt] = (f32x4){0.f, 0.f, 0.f, 0.f};
    }
#pragma unroll
    for (int ks = 0; ks < 4; ++ks)
#pragma unroll
      for (int nt = 0; nt < 4; ++nt) {
        kacc[nt] = __builtin_amdgcn_mfma_f32_16x16x32_bf16(
            ka[ks], wfrag[(16 + ks * 4 + nt) * 64 + lane], kacc[nt], 0, 0, 0);
        vacc[nt] = __builtin_amdgcn_mfma_f32_16x16x32_bf16(
            ka[ks], wfrag[(32 + ks * 4 + nt) * 64 + lane], vacc[nt], 0, 0, 0);
      }

    // D rows: m = quad*4 + reg -> pixel mt*4+quad, uv = reg.
    // logits: q (staged, scaled) dot k over head channels; head's 8 channels
    // live in the 8 lanes {same quad, same l15>>3, l15 low3 varying}.
    const int opix = hw0 + wv * 16 + mt * 4 + quad;
    float qv[4];
#pragma unroll
    for (int nt = 0; nt < 4; ++nt)
      qv[nt] = q_sf[(wv * 16 + mt * 4 + quad) * 68 + nt * 16 + l15];

#pragma unroll
    for (int nt = 0; nt < 4; ++nt) {
      float lg[4];
#pragma unroll
      for (int r = 0; r < 4; ++r) {
        float p = qv[nt] * (kacc[nt][r] + kb[nt]);
        p += __shfl_xor(p, 1);
        p += __shfl_xor(p, 2);
        p += __shfl_xor(p, 4);
        lg[r] = p;
      }
      float mx = fmaxf(fmaxf(lg[0], lg[1]), fmaxf(lg[2], lg[3]));
      float e0 = __expf(lg[0] - mx), e1 = __expf(lg[1] - mx);
      float e2 = __expf(lg[2] - mx), e3 = __expf(lg[3] - mx);
      float inv = 1.0f / (e0 + e1 + e2 + e3);
      float o = (e0 * vacc[nt][0] + e1 * vacc[nt][1] +
                 e2 * vacc[nt][2] + e3 * vacc[nt][3]) * inv + vb[nt];
      out[(b * 64 + nt * 16 + l15) * HWHW + opix] = o;
    }
  }
}

extern "C" void kernel_launch(void* const* d_in, const int* in_sizes, int n_in,
                              void* d_out, int out_size, void* d_ws, size_t ws_size,
                              hipStream_t stream) {
  const float* feat_supp = (const float*)d_in[0];
  const float* flow      = (const float*)d_in[1];
  const float* feat_curr = (const float*)d_in[2];
  const float* q_w = (const float*)d_in[3];
  const float* q_b = (const float*)d_in[4];
  const float* k_w = (const float*)d_in[5];
  const float* k_b = (const float*)d_in[6];
  const float* v_w = (const float*)d_in[7];
  const float* v_b = (const float*)d_in[8];
  float* out = (float*)d_out;
  (void)in_sizes; (void)n_in; (void)out_size; (void)ws_size;

  __hip_bfloat16* wfrag = (__hip_bfloat16*)d_ws;   // 49152 B
  hipLaunchKernelGGL(pack_weights, dim3(12), dim3(256), 0, stream,
                     q_w, k_w, v_w, wfrag);
  hipLaunchKernelGGL(iw_main, dim3(2048), dim3(256), 0, stream,
                     feat_supp, flow, feat_curr, (const short8*)wfrag,
                     q_b, k_b, v_b, out);
}